// Round 6
// baseline (510.673 us; speedup 1.0000x reference)
//
#include <hip/hip_runtime.h>
#include <hip/hip_cooperative_groups.h>

namespace cg = cooperative_groups;

// Problem geometry (compile-time constants from the reference)
#define N_TOTAL 500000
#define C 128
#define G 32
#define NB 8
#define EPS 1e-5f
#define NBLOCKS 2048
#define RPB ((N_TOTAL + NBLOCKS - 1) / NBLOCKS)   // 245 rows per block

typedef float f4 __attribute__((ext_vector_type(4)));

// cumulative boundaries of LENGTHS = {40000,55000,70000,45000,80000,65000,90000,55000}
__device__ __forceinline__ int cloud_of(int i) {
    int c = 0;
    c += (i >= 40000);
    c += (i >= 95000);
    c += (i >= 165000);
    c += (i >= 210000);
    c += (i >= 290000);
    c += (i >= 355000);
    c += (i >= 445000);
    return c;
}

// element counts per (cloud, group) = LENGTHS[b] * (C/G)
__device__ const float d_cnt[NB] = {160000.f, 220000.f, 280000.f, 180000.f,
                                    320000.f, 260000.f, 360000.f, 220000.f};

// ws layout: float ws[0..255]=sum[cloud][group], ws[256..511]=sumsq;
// cid = (uint8*)ws + 4096, N_TOTAL bytes: cloud id per ORIGINAL row index.

// ---------------- fused cooperative kernel ----------------
// phase 0: zero ws, scatter cid[perm[i]] = cloud_of(i)   (~2.5 MB)
// phase 1: sequential stats sweep (fills L3 with feats)   (256 MB HBM read)
// phase 2: finalize + normalize; feats re-read hits L3; nt stores for out
__global__ __launch_bounds__(256, 8) void gn_fused(const float* __restrict__ feats,
                                                   const float* __restrict__ gamma,
                                                   const float* __restrict__ beta,
                                                   const int* __restrict__ perm,
                                                   float* __restrict__ ws,
                                                   unsigned char* __restrict__ cid,
                                                   float* __restrict__ out) {
    cg::grid_group grid = cg::this_grid();
    const int tid = threadIdx.x;
    const int gid = blockIdx.x * 256 + tid;

    // ---------- phase 0 ----------
    if (gid < 2 * NB * G) ws[gid] = 0.f;
    for (int i = gid; i < N_TOTAL; i += NBLOCKS * 256)
        cid[perm[i]] = (unsigned char)cloud_of(i);

    grid.sync();

    // ---------- phase 1: stats ----------
    __shared__ float lacc[2 * NB * G];
    for (int k = tid; k < 2 * NB * G; k += 256) lacc[k] = 0.f;
    __syncthreads();

    const int g = tid & 31;      // group / float4 slot within row
    const int rsub = tid >> 5;   // 0..7: row within 8-row iteration
    int start = blockIdx.x * RPB;
    int end = start + RPB;
    if (end > N_TOTAL) end = N_TOTAL;

    float s[NB], ss[NB];
#pragma unroll
    for (int b = 0; b < NB; b++) { s[b] = 0.f; ss[b] = 0.f; }

#pragma unroll 4
    for (int row = start + rsub; row < end; row += 8) {
        int cl = cid[row];
        f4 v = ((const f4*)(feats + ((long long)row << 7)))[g];
        float rs = v.x + v.y + v.z + v.w;
        float rss = v.x * v.x + v.y * v.y + v.z * v.z + v.w * v.w;
#pragma unroll
        for (int b = 0; b < NB; b++) {
            if (cl == b) { s[b] += rs; ss[b] += rss; }
        }
    }
#pragma unroll
    for (int b = 0; b < NB; b++) {
        if (s[b] != 0.f || ss[b] != 0.f) {
            atomicAdd(&lacc[b * G + g], s[b]);
            atomicAdd(&lacc[NB * G + b * G + g], ss[b]);
        }
    }
    __syncthreads();

    for (int k = tid; k < 2 * NB * G; k += 256) {
        float a = lacc[k];
        if (a != 0.f) atomicAdd(&ws[k], a);
    }

    grid.sync();

    // ---------- phase 2: finalize + apply ----------
    __shared__ float lmean[NB * G];
    __shared__ float linv[NB * G];
    {
        float sm = ws[tid];
        float sq = ws[NB * G + tid];
        float cnt = d_cnt[tid >> 5];
        float m = sm / cnt;
        float var = sq / cnt - m * m;
        lmean[tid] = m;
        linv[tid] = rsqrtf(var + EPS);
    }
    __syncthreads();

    f4 gm = ((const f4*)gamma)[g];
    f4 bt = ((const f4*)beta)[g];

#pragma unroll 4
    for (int row = start + rsub; row < end; row += 8) {
        int cl = cid[row];
        f4 v = ((const f4*)(feats + ((long long)row << 7)))[g];
        float m = lmean[cl * G + g];
        float inv = linv[cl * G + g];
        f4 y;
        y.x = (v.x - m) * inv * gm.x + bt.x;
        y.y = (v.y - m) * inv * gm.y + bt.y;
        y.z = (v.z - m) * inv * gm.z + bt.z;
        y.w = (v.w - m) * inv * gm.w + bt.w;
        __builtin_nontemporal_store(y, (f4*)(out + ((long long)row << 7)) + g);
    }
}

// ---------------- fallback path (plain launches, known-good) ----------------
__global__ __launch_bounds__(256) void gn_prep(const int* __restrict__ perm,
                                               unsigned char* __restrict__ cid,
                                               float* __restrict__ ws) {
    int gid = blockIdx.x * 256 + threadIdx.x;
    if (gid < 2 * NB * G) ws[gid] = 0.f;
    int stride = gridDim.x * 256;
    for (int i = gid; i < N_TOTAL; i += stride)
        cid[perm[i]] = (unsigned char)cloud_of(i);
}

__global__ __launch_bounds__(256) void gn_stats(const float* __restrict__ feats,
                                                const unsigned char* __restrict__ cid,
                                                float* __restrict__ ws) {
    __shared__ float lacc[2 * NB * G];
    int tid = threadIdx.x;
    for (int k = tid; k < 2 * NB * G; k += 256) lacc[k] = 0.f;
    __syncthreads();
    const int g = tid & 31;
    const int rsub = tid >> 5;
    int start = blockIdx.x * RPB;
    int end = start + RPB;
    if (end > N_TOTAL) end = N_TOTAL;
    float s[NB], ss[NB];
#pragma unroll
    for (int b = 0; b < NB; b++) { s[b] = 0.f; ss[b] = 0.f; }
#pragma unroll 4
    for (int row = start + rsub; row < end; row += 8) {
        int cl = cid[row];
        f4 v = ((const f4*)(feats + ((long long)row << 7)))[g];
        float rs = v.x + v.y + v.z + v.w;
        float rss = v.x * v.x + v.y * v.y + v.z * v.z + v.w * v.w;
#pragma unroll
        for (int b = 0; b < NB; b++)
            if (cl == b) { s[b] += rs; ss[b] += rss; }
    }
#pragma unroll
    for (int b = 0; b < NB; b++) {
        if (s[b] != 0.f || ss[b] != 0.f) {
            atomicAdd(&lacc[b * G + g], s[b]);
            atomicAdd(&lacc[NB * G + b * G + g], ss[b]);
        }
    }
    __syncthreads();
    for (int k = tid; k < 2 * NB * G; k += 256) {
        float a = lacc[k];
        if (a != 0.f) atomicAdd(&ws[k], a);
    }
}

__global__ __launch_bounds__(256) void gn_apply(const float* __restrict__ feats,
                                                const unsigned char* __restrict__ cid,
                                                const float* __restrict__ gamma,
                                                const float* __restrict__ beta,
                                                const float* __restrict__ ws,
                                                float* __restrict__ out) {
    __shared__ float lmean[NB * G];
    __shared__ float linv[NB * G];
    int tid = threadIdx.x;
    {
        float sm = ws[tid];
        float sq = ws[NB * G + tid];
        float cnt = d_cnt[tid >> 5];
        float m = sm / cnt;
        float var = sq / cnt - m * m;
        lmean[tid] = m;
        linv[tid] = rsqrtf(var + EPS);
    }
    __syncthreads();
    const int g = tid & 31;
    const int rsub = tid >> 5;
    f4 gm = ((const f4*)gamma)[g];
    f4 bt = ((const f4*)beta)[g];
    int start = blockIdx.x * RPB;
    int end = start + RPB;
    if (end > N_TOTAL) end = N_TOTAL;
#pragma unroll 4
    for (int row = start + rsub; row < end; row += 8) {
        int cl = cid[row];
        f4 v = ((const f4*)(feats + ((long long)row << 7)))[g];
        float m = lmean[cl * G + g];
        float inv = linv[cl * G + g];
        f4 y;
        y.x = (v.x - m) * inv * gm.x + bt.x;
        y.y = (v.y - m) * inv * gm.y + bt.y;
        y.z = (v.z - m) * inv * gm.z + bt.z;
        y.w = (v.w - m) * inv * gm.w + bt.w;
        __builtin_nontemporal_store(y, (f4*)(out + ((long long)row << 7)) + g);
    }
}

extern "C" void kernel_launch(void* const* d_in, const int* in_sizes, int n_in,
                              void* d_out, int out_size, void* d_ws, size_t ws_size,
                              hipStream_t stream) {
    const float* feats = (const float*)d_in[0];
    const float* gamma = (const float*)d_in[1];
    const float* beta  = (const float*)d_in[2];
    const int*   perm  = (const int*)d_in[3];
    float* out = (float*)d_out;
    float* ws  = (float*)d_ws;
    unsigned char* cid = (unsigned char*)d_ws + 4096;

    void* args[] = {(void*)&feats, (void*)&gamma, (void*)&beta, (void*)&perm,
                    (void*)&ws, (void*)&cid, (void*)&out};
    hipError_t err = hipLaunchCooperativeKernel((const void*)gn_fused,
                                                dim3(NBLOCKS), dim3(256),
                                                args, 0, stream);
    if (err != hipSuccess) {
        // Deterministic fallback: plain 3-kernel path (L3 still persists
        // across kernel boundaries; only the launch/drain overhead returns).
        gn_prep<<<512, 256, 0, stream>>>(perm, cid, ws);
        gn_stats<<<NBLOCKS, 256, 0, stream>>>(feats, cid, ws);
        gn_apply<<<NBLOCKS, 256, 0, stream>>>(feats, cid, gamma, beta, ws, out);
    }
}

// Round 7
// 174.058 us; speedup vs baseline: 2.9339x; 2.9339x over previous
//
#include <hip/hip_runtime.h>

// Problem geometry (compile-time constants from the reference)
#define N_TOTAL 500000
#define C 128
#define G 32
#define NB 8
#define EPS 1e-5f
#define NBLK 2048
#define RPB ((N_TOTAL + NBLK - 1) / NBLK)   // 245 rows per block

typedef float f4 __attribute__((ext_vector_type(4)));

// cumulative boundaries of LENGTHS = {40000,55000,70000,45000,80000,65000,90000,55000}
__device__ __forceinline__ int cloud_of(int i) {
    int c = 0;
    c += (i >= 40000);
    c += (i >= 95000);
    c += (i >= 165000);
    c += (i >= 210000);
    c += (i >= 290000);
    c += (i >= 355000);
    c += (i >= 445000);
    return c;
}

// element counts per (cloud, group) = LENGTHS[b] * (C/G)
__device__ const float d_cnt[NB] = {160000.f, 220000.f, 280000.f, 180000.f,
                                    320000.f, 260000.f, 360000.f, 220000.f};

// ws layout: float ws[0..255]=sum[cloud][group], ws[256..511]=sumsq;
// cid = (uint8*)ws + 4096, N_TOTAL bytes: cloud id per ORIGINAL row index.

// Kernel 1: zero ws + scatter cloud ids (cid[perm[i]] = cloud_of(i)). ~2.5 MB.
__global__ __launch_bounds__(256) void gn_prep(const int* __restrict__ perm,
                                               unsigned char* __restrict__ cid,
                                               float* __restrict__ ws) {
    int gid = blockIdx.x * 256 + threadIdx.x;
    if (gid < 2 * NB * G) ws[gid] = 0.f;
    for (int i = gid; i < N_TOTAL; i += 512 * 256)
        cid[perm[i]] = (unsigned char)cloud_of(i);
}

// accumulate one row into the 8 per-cloud register buckets (compile-time index)
#define ACCUM(v, cl)                                                          \
    do {                                                                      \
        float rs_ = (v).x + (v).y + (v).z + (v).w;                            \
        float rss_ = (v).x * (v).x + (v).y * (v).y + (v).z * (v).z +          \
                     (v).w * (v).w;                                           \
        _Pragma("unroll")                                                     \
        for (int b = 0; b < NB; b++)                                          \
            if ((cl) == b) { s[b] += rs_; ss[b] += rss_; }                    \
    } while (0)

// Kernel 2: sequential stats sweep, unroll-by-4 for MLP (fills L3 with feats).
__global__ __launch_bounds__(256) void gn_stats(const float* __restrict__ feats,
                                                const unsigned char* __restrict__ cid,
                                                float* __restrict__ ws) {
    __shared__ float lacc[2 * NB * G];
    int tid = threadIdx.x;
    for (int k = tid; k < 2 * NB * G; k += 256) lacc[k] = 0.f;
    __syncthreads();

    const int g = tid & 31;      // float4 slot (group) within row
    const int rsub = tid >> 5;   // 0..7 row-slot within 8-row stripe
    int start = blockIdx.x * RPB;
    int end = start + RPB;
    if (end > N_TOTAL) end = N_TOTAL;

    float s[NB], ss[NB];
#pragma unroll
    for (int b = 0; b < NB; b++) { s[b] = 0.f; ss[b] = 0.f; }

    int row = start + rsub;
    // 4 independent rows in flight per thread
    for (; row + 24 < end; row += 32) {
        int c0 = cid[row], c1 = cid[row + 8], c2 = cid[row + 16], c3 = cid[row + 24];
        f4 v0 = ((const f4*)(feats + ((long long)(row)      << 7)))[g];
        f4 v1 = ((const f4*)(feats + ((long long)(row + 8)  << 7)))[g];
        f4 v2 = ((const f4*)(feats + ((long long)(row + 16) << 7)))[g];
        f4 v3 = ((const f4*)(feats + ((long long)(row + 24) << 7)))[g];
        ACCUM(v0, c0); ACCUM(v1, c1); ACCUM(v2, c2); ACCUM(v3, c3);
    }
    for (; row < end; row += 8) {
        int c0 = cid[row];
        f4 v0 = ((const f4*)(feats + ((long long)row << 7)))[g];
        ACCUM(v0, c0);
    }

#pragma unroll
    for (int b = 0; b < NB; b++) {
        if (s[b] != 0.f || ss[b] != 0.f) {
            atomicAdd(&lacc[b * G + g], s[b]);
            atomicAdd(&lacc[NB * G + b * G + g], ss[b]);
        }
    }
    __syncthreads();

    for (int k = tid; k < 2 * NB * G; k += 256) {
        float a = lacc[k];
        if (a != 0.f) atomicAdd(&ws[k], a);
    }
}

// Kernel 3: finalize + sequential normalize/affine; nt stores so `out`
// doesn't evict feats from L3 (feats re-read should be L3-served).
__global__ __launch_bounds__(256) void gn_apply(const float* __restrict__ feats,
                                                const unsigned char* __restrict__ cid,
                                                const float* __restrict__ gamma,
                                                const float* __restrict__ beta,
                                                const float* __restrict__ ws,
                                                float* __restrict__ out) {
    __shared__ float lmean[NB * G];
    __shared__ float linv[NB * G];
    int tid = threadIdx.x;
    {
        float sm = ws[tid];
        float sq = ws[NB * G + tid];
        float cnt = d_cnt[tid >> 5];
        float m = sm / cnt;
        float var = sq / cnt - m * m;
        lmean[tid] = m;
        linv[tid] = rsqrtf(var + EPS);
    }
    __syncthreads();

    const int g = tid & 31;
    const int rsub = tid >> 5;
    f4 gm = ((const f4*)gamma)[g];
    f4 bt = ((const f4*)beta)[g];

    int start = blockIdx.x * RPB;
    int end = start + RPB;
    if (end > N_TOTAL) end = N_TOTAL;

#define NORM1(v, cl, r)                                                       \
    do {                                                                      \
        float m_ = lmean[(cl) * G + g];                                       \
        float i_ = linv[(cl) * G + g];                                        \
        f4 y_;                                                                \
        y_.x = ((v).x - m_) * i_ * gm.x + bt.x;                               \
        y_.y = ((v).y - m_) * i_ * gm.y + bt.y;                               \
        y_.z = ((v).z - m_) * i_ * gm.z + bt.z;                               \
        y_.w = ((v).w - m_) * i_ * gm.w + bt.w;                               \
        __builtin_nontemporal_store(y_, (f4*)(out + ((long long)(r) << 7)) + g); \
    } while (0)

    int row = start + rsub;
    for (; row + 24 < end; row += 32) {
        int c0 = cid[row], c1 = cid[row + 8], c2 = cid[row + 16], c3 = cid[row + 24];
        f4 v0 = ((const f4*)(feats + ((long long)(row)      << 7)))[g];
        f4 v1 = ((const f4*)(feats + ((long long)(row + 8)  << 7)))[g];
        f4 v2 = ((const f4*)(feats + ((long long)(row + 16) << 7)))[g];
        f4 v3 = ((const f4*)(feats + ((long long)(row + 24) << 7)))[g];
        NORM1(v0, c0, row);
        NORM1(v1, c1, row + 8);
        NORM1(v2, c2, row + 16);
        NORM1(v3, c3, row + 24);
    }
    for (; row < end; row += 8) {
        int c0 = cid[row];
        f4 v0 = ((const f4*)(feats + ((long long)row << 7)))[g];
        NORM1(v0, c0, row);
    }
#undef NORM1
}

extern "C" void kernel_launch(void* const* d_in, const int* in_sizes, int n_in,
                              void* d_out, int out_size, void* d_ws, size_t ws_size,
                              hipStream_t stream) {
    const float* feats = (const float*)d_in[0];
    const float* gamma = (const float*)d_in[1];
    const float* beta  = (const float*)d_in[2];
    const int*   perm  = (const int*)d_in[3];
    float* out = (float*)d_out;
    float* ws  = (float*)d_ws;
    unsigned char* cid = (unsigned char*)d_ws + 4096;

    gn_prep<<<512, 256, 0, stream>>>(perm, cid, ws);
    gn_stats<<<NBLK, 256, 0, stream>>>(feats, cid, ws);
    gn_apply<<<NBLK, 256, 0, stream>>>(feats, cid, gamma, beta, ws, out);
}